// Round 1
// baseline (176.344 us; speedup 1.0000x reference)
//
#include <hip/hip_runtime.h>
#include <math.h>

#define NN 128   // nodes (C_OUT)
#define ND 40    // node_dim
#define BB 32    // batch
#define CC 64    // channels
#define LL 64    // length
#define GDIM (CC*LL)  // 4096

// ---------------------------------------------------------------------------
// K1a: Sg = relu(nv1 @ nv2), 128x128, row-major. 64 blocks x 256 threads.
__global__ __launch_bounds__(256) void k_s(const float* __restrict__ nv1,
                                           const float* __restrict__ nv2,
                                           float* __restrict__ Sg) {
    int idx = blockIdx.x * 256 + threadIdx.x;   // 16384 threads
    int v = idx >> 7, w = idx & (NN - 1);
    float s = 0.f;
#pragma unroll
    for (int k = 0; k < ND; ++k) s = fmaf(nv1[v * ND + k], nv2[k * NN + w], s);
    Sg[idx] = fmaxf(s, 0.f);
}

// ---------------------------------------------------------------------------
// K1b: per-row softmax + self-loop + row-normalize -> A (row-major).
// One wave per row: 64 blocks x 128 threads (2 rows/block).
__global__ __launch_bounds__(128) void k_soft(const float* __restrict__ Sg,
                                              float* __restrict__ A) {
    int t = threadIdx.x;
    int r = blockIdx.x * 2 + (t >> 6);
    int l = t & 63;
    float s0 = Sg[r * NN + l], s1 = Sg[r * NN + 64 + l];
    float m = fmaxf(s0, s1);
#pragma unroll
    for (int d = 32; d; d >>= 1) m = fmaxf(m, __shfl_xor(m, d));
    float e0 = expf(s0 - m), e1 = expf(s1 - m);
    float ss = e0 + e1;
#pragma unroll
    for (int d = 32; d; d >>= 1) ss += __shfl_xor(ss, d);
    float p0 = e0 / ss, p1 = e1 / ss;
    // row sum of adp (numerically), + 1 for the self loop
    float ps = p0 + p1;
#pragma unroll
    for (int d = 32; d; d >>= 1) ps += __shfl_xor(ps, d);
    float ra = 1.f / (ps + 1.f);
    A[r * NN + l]      = (p0 + (l == r ? 1.f : 0.f)) * ra;
    A[r * NN + 64 + l] = (p1 + ((l + 64) == r ? 1.f : 0.f)) * ra;
}

// ---------------------------------------------------------------------------
// K2: A2 = A @ A. 64 blocks x 256 threads, one element each.
__global__ __launch_bounds__(256) void k_a2(const float* __restrict__ A,
                                            float* __restrict__ A2) {
    int idx = blockIdx.x * 256 + threadIdx.x;
    int w = idx >> 7, v = idx & (NN - 1);
    float s = 0.f;
    for (int u = 0; u < NN; ++u) s = fmaf(A[w * NN + u], A[u * NN + v], s);
    A2[idx] = s;
}

// ---------------------------------------------------------------------------
// K3: fold everything into Mt (transposed: Mt[v][o]).
// M[o,v] = W0[o,v] + sum_w W1[o,w]*P[w,v] + W2[o,w]*H2[w,v]
//   P  = 0.5 I + 0.5 A
//   H2 = 0.5 I + 0.25 A + 0.25 A^2
__global__ __launch_bounds__(256) void k_m(const float* __restrict__ A,
                                           const float* __restrict__ A2,
                                           const float* __restrict__ W,
                                           float* __restrict__ Mt) {
    int idx = blockIdx.x * 256 + threadIdx.x;
    int o = idx >> 7, v = idx & (NN - 1);
    float m = W[o * 384 + v];
    for (int w = 0; w < NN; ++w) {
        float d  = (w == v) ? 1.f : 0.f;
        float a  = A[w * NN + v];
        float a2 = A2[w * NN + v];
        float p  = 0.5f * d + 0.5f * a;
        float h2 = 0.5f * d + 0.25f * a + 0.25f * a2;
        m = fmaf(W[o * 384 + 128 + w], p, m);
        m = fmaf(W[o * 384 + 256 + w], h2, m);
    }
    Mt[v * NN + o] = m;
}

// ---------------------------------------------------------------------------
// Main kernel: one block per (b, c). 256 threads, 8v x 4l register tile each.
//  o[v,l] = sum_u M[v,u] x[u,l];  y = x + gelu(o + bias);  LN over v; write out.
__global__ __launch_bounds__(256) void k_main(const float* __restrict__ x,
                                              const float* __restrict__ Mt,
                                              const float* __restrict__ cb,
                                              const float* __restrict__ lnw,
                                              const float* __restrict__ lnb,
                                              float* __restrict__ out) {
    extern __shared__ float sm[];
    float* xs = sm;                        // [128][64]  x slice
    float* Ms = sm + NN * LL;              // [128][128] Mt (Ms[u*128+v] = M[v,u])
    float* yt = sm + NN * LL + NN * NN;    // [64][129]  y transposed, padded
    __shared__ float cbs[NN], lnws[NN], lnbs[NN];
    __shared__ float psum[4][LL], psq[4][LL], mu[LL], rsg[LL];

    const int t = threadIdx.x;
    const int c = blockIdx.x, b = blockIdx.y;

    // stage Mt (16384 floats)
    {
        const float4* src = (const float4*)Mt;
        float4* dst = (float4*)Ms;
#pragma unroll
        for (int k = 0; k < 16; ++k) dst[t + k * 256] = src[t + k * 256];
    }
    // stage x slice: x[b, v, c, l] -> xs[v][l]
    {
        const float* xsrc = x + b * (NN * GDIM) + c * LL;
        float4* dst = (float4*)xs;
#pragma unroll
        for (int k = 0; k < 8; ++k) {
            int i = t + k * 256;           // 2048 float4s
            int v = i >> 4, l4 = i & 15;
            dst[i] = *(const float4*)(xsrc + v * GDIM + l4 * 4);
        }
    }
    if (t < NN) { cbs[t] = cb[t]; lnws[t] = lnw[t]; lnbs[t] = lnb[t]; }
    __syncthreads();

    const int tl = t & 15, tv = t >> 4;
    const int l0 = tl * 4, v0 = tv * 8;

    float acc[8][4];
#pragma unroll
    for (int i = 0; i < 8; ++i)
#pragma unroll
        for (int j = 0; j < 4; ++j) acc[i][j] = 0.f;

#pragma unroll 2
    for (int u = 0; u < NN; ++u) {
        float4 xv = ((const float4*)(xs + u * LL))[tl];
        float4 ma = ((const float4*)(Ms + u * NN))[tv * 2];
        float4 mb = ((const float4*)(Ms + u * NN))[tv * 2 + 1];
        float mr[8] = {ma.x, ma.y, ma.z, ma.w, mb.x, mb.y, mb.z, mb.w};
        float xr[4] = {xv.x, xv.y, xv.z, xv.w};
#pragma unroll
        for (int i = 0; i < 8; ++i)
#pragma unroll
            for (int j = 0; j < 4; ++j)
                acc[i][j] = fmaf(mr[i], xr[j], acc[i][j]);
    }

    // epilogue: bias + exact gelu + residual -> yt[l][v] (129-padded)
#pragma unroll
    for (int i = 0; i < 8; ++i) {
        float4 xo = ((const float4*)(xs + (v0 + i) * LL))[tl];
        float xr[4] = {xo.x, xo.y, xo.z, xo.w};
        float bias = cbs[v0 + i];
#pragma unroll
        for (int j = 0; j < 4; ++j) {
            float o = acc[i][j] + bias;
            float g = 0.5f * o * (1.f + erff(o * 0.70710678118f));
            yt[(l0 + j) * 129 + v0 + i] = xr[j] + g;
        }
    }
    __syncthreads();

    // LayerNorm over v (128) per pixel l
    {
        int l = t & 63, q = t >> 6;
        float s = 0.f, s2 = 0.f;
#pragma unroll
        for (int v = 0; v < 32; ++v) {
            float y = yt[l * 129 + q * 32 + v];
            s += y;
            s2 = fmaf(y, y, s2);
        }
        psum[q][l] = s;
        psq[q][l] = s2;
    }
    __syncthreads();
    if (t < 64) {
        float s  = psum[0][t] + psum[1][t] + psum[2][t] + psum[3][t];
        float s2 = psq[0][t] + psq[1][t] + psq[2][t] + psq[3][t];
        float mean = s * (1.f / NN);
        float var = s2 * (1.f / NN) - mean * mean;
        mu[t] = mean;
        rsg[t] = rsqrtf(var + 1e-5f);
    }
    __syncthreads();

    // write out[b, c*64+l, v], coalesced in v
    float* op = out + (b * GDIM + c * LL) * NN;
#pragma unroll
    for (int k = 0; k < 32; ++k) {
        int i = t + k * 256;               // 8192 elements
        int v = i & 127, l = i >> 7;
        float yv = (yt[l * 129 + v] - mu[l]) * rsg[l] * lnws[v] + lnbs[v];
        op[l * NN + v] = yv;
    }
}

// ---------------------------------------------------------------------------
extern "C" void kernel_launch(void* const* d_in, const int* in_sizes, int n_in,
                              void* d_out, int out_size, void* d_ws, size_t ws_size,
                              hipStream_t stream) {
    const float* x   = (const float*)d_in[0];
    const float* nv1 = (const float*)d_in[1];
    const float* nv2 = (const float*)d_in[2];
    const float* cw  = (const float*)d_in[3];
    const float* cb  = (const float*)d_in[4];
    const float* lnw = (const float*)d_in[5];
    const float* lnb = (const float*)d_in[6];
    float* out = (float*)d_out;

    // scratch: Sg, A, A2 live in d_out (fully overwritten by k_main afterwards);
    // Mt lives in d_ws (64 KB) since k_main reads it while writing d_out.
    float* Sg = out;
    float* A  = out + NN * NN;
    float* A2 = out + 2 * NN * NN;
    float* Mt = (float*)d_ws;

    k_s   <<<64, 256, 0, stream>>>(nv1, nv2, Sg);
    k_soft<<<64, 128, 0, stream>>>(Sg, A);
    k_a2  <<<64, 256, 0, stream>>>(A, A2);
    k_m   <<<64, 256, 0, stream>>>(A, A2, cw, Mt);

    size_t shmem = (size_t)(NN * LL + NN * NN + LL * 129) * sizeof(float);
    k_main<<<dim3(CC, BB), 256, shmem, stream>>>(x, Mt, cb, lnw, lnb, out);
}

// Round 2
// 141.409 us; speedup vs baseline: 1.2470x; 1.2470x over previous
//
#include <hip/hip_runtime.h>
#include <hip/hip_bf16.h>
#include <math.h>

#define NN 128   // nodes (C_OUT)
#define ND 40    // node_dim
#define BB 32    // batch
#define CC 64    // channels
#define LL 64    // length
#define GDIM (CC*LL)  // 4096

// ---------------------------------------------------------------------------
// K1: fused relu(nv1@nv2) + row softmax + self-loop + row-normalize -> A.
// One wave per row: 64 blocks x 128 threads (2 rows/block).
__global__ __launch_bounds__(128) void k_adj(const float* __restrict__ nv1,
                                             const float* __restrict__ nv2,
                                             float* __restrict__ A) {
    int t = threadIdx.x;
    int r = blockIdx.x * 2 + (t >> 6);
    int l = t & 63;
    float s0 = 0.f, s1 = 0.f;
#pragma unroll
    for (int k = 0; k < ND; ++k) {
        float a = nv1[r * ND + k];
        s0 = fmaf(a, nv2[k * NN + l], s0);
        s1 = fmaf(a, nv2[k * NN + 64 + l], s1);
    }
    s0 = fmaxf(s0, 0.f);
    s1 = fmaxf(s1, 0.f);
    float m = fmaxf(s0, s1);
#pragma unroll
    for (int d = 32; d; d >>= 1) m = fmaxf(m, __shfl_xor(m, d));
    float e0 = expf(s0 - m), e1 = expf(s1 - m);
    float ss = e0 + e1;
#pragma unroll
    for (int d = 32; d; d >>= 1) ss += __shfl_xor(ss, d);
    float p0 = e0 / ss, p1 = e1 / ss;
    float ps = p0 + p1;
#pragma unroll
    for (int d = 32; d; d >>= 1) ps += __shfl_xor(ps, d);
    float ra = 1.f / (ps + 1.f);
    A[r * NN + l]      = (p0 + (l == r ? 1.f : 0.f)) * ra;
    A[r * NN + 64 + l] = (p1 + ((l + 64) == r ? 1.f : 0.f)) * ra;
}

// ---------------------------------------------------------------------------
// K2: A2 = A @ A. 64 blocks x 256 threads, one element each.
__global__ __launch_bounds__(256) void k_a2(const float* __restrict__ A,
                                            float* __restrict__ A2) {
    int idx = blockIdx.x * 256 + threadIdx.x;
    int w = idx >> 7, v = idx & (NN - 1);
    float s = 0.f;
    for (int u = 0; u < NN; ++u) s = fmaf(A[w * NN + u], A[u * NN + v], s);
    A2[idx] = s;
}

// ---------------------------------------------------------------------------
// K3: fold into Mreg, fragment-ready layout for k_main's register tiling.
// M[o,k] = W0[o,k] + sum_w W1[o,w]*P[w,k] + W2[o,w]*H2[w,k]
//   P  = 0.5 I + 0.5 A ;  H2 = 0.5 I + 0.25 A + 0.25 A^2
// Layout: lane t of k_main (t=0..255) owns rows {2rg,2rg+1}, k-quarter kg,
//   rg = (t>>6)*16 + (t&15), kg = (t>>4)&3.
//   Mreg[t*64 + j]: j<32 -> M[2rg][kg*32+j], j>=32 -> M[2rg+1][kg*32+j-32].
__global__ __launch_bounds__(256) void k_m(const float* __restrict__ A,
                                           const float* __restrict__ A2,
                                           const float* __restrict__ W,
                                           float* __restrict__ Mreg) {
    int idx = blockIdx.x * 256 + threadIdx.x;
    int o = idx >> 7, v = idx & (NN - 1);   // o = output row, v = k index
    float m = W[o * 384 + v];
    for (int w = 0; w < NN; ++w) {
        float d  = (w == v) ? 1.f : 0.f;
        float a  = A[w * NN + v];
        float a2 = A2[w * NN + v];
        float p  = 0.5f * d + 0.5f * a;
        float h2 = 0.5f * d + 0.25f * a + 0.25f * a2;
        m = fmaf(W[o * 384 + 128 + w], p, m);
        m = fmaf(W[o * 384 + 256 + w], h2, m);
    }
    int rg = o >> 1, rp = o & 1;
    int t  = (rg >> 4) * 64 + ((v >> 5) << 4) + (rg & 15);
    int j  = rp * 32 + (v & 31);
    Mreg[t * 64 + j] = m;
}

// ---------------------------------------------------------------------------
// Main kernel: one block per (b, c). 256 threads, 4 waves.
// Lane owns rows {2rg, 2rg+1} and k-quarter kg; M in 64 VGPRs; x broadcast
// from swizzled LDS; k-quarters combined via shfl_xor(16/32).
__global__ __launch_bounds__(256, 3) void k_main(const float* __restrict__ x,
                                                 const float* __restrict__ Mreg,
                                                 const float* __restrict__ cb,
                                                 const float* __restrict__ lnw,
                                                 const float* __restrict__ lnb,
                                                 float* __restrict__ out) {
    __shared__ float xs[NN * LL];                 // swizzled: [k][p ^ ((k>>5)<<4)]
    __shared__ __hip_bfloat16 yt[LL * 130];       // [p][v], row stride 130
    __shared__ float cbs[NN], lnws[NN], lnbs[NN];
    __shared__ float mu[LL], rsg[LL];

    const int t = threadIdx.x;
    const int c = blockIdx.x, b = blockIdx.y;
    const int w = t >> 6, l = t & 63;
    const int rg = w * 16 + (l & 15);
    const int kg = (l >> 4) & 3;
    const int r0 = rg * 2;
    const int kbase = kg * 32;
    const int psw = kg << 4;                      // read-side pixel swizzle

    // ---- M into registers (64 floats/lane, coalesces through L1/L2) ----
    float m0[32], m1[32];
    {
        const float4* mp = (const float4*)(Mreg + t * 64);
#pragma unroll
        for (int j = 0; j < 8; ++j) {
            float4 q = mp[j];
            m0[4*j] = q.x; m0[4*j+1] = q.y; m0[4*j+2] = q.z; m0[4*j+3] = q.w;
        }
#pragma unroll
        for (int j = 0; j < 8; ++j) {
            float4 q = mp[8 + j];
            m1[4*j] = q.x; m1[4*j+1] = q.y; m1[4*j+2] = q.z; m1[4*j+3] = q.w;
        }
    }

    // ---- stage x slice -> xs (swizzled) ----
    {
        const float* xsrc = x + (size_t)b * NN * GDIM + (size_t)c * LL;
#pragma unroll
        for (int kk = 0; kk < 8; ++kk) {
            int i = t + kk * 256;                 // 2048 float4 slots
            int v = i >> 4, p4 = (i & 15) * 4;
            float4 q = *(const float4*)(xsrc + v * GDIM + p4);
            *(float4*)(xs + v * 64 + (p4 ^ ((v >> 5) << 4))) = q;
        }
    }
    if (t < NN) { cbs[t] = cb[t]; lnws[t] = lnw[t]; lnbs[t] = lnb[t]; }
    __syncthreads();

    // ---- compute: 4 chunks of 16 pixels ----
    for (int ch = 0; ch < 4; ++ch) {
        const int p0 = ch * 16;
        float a0[16], a1[16];
#pragma unroll
        for (int i = 0; i < 16; ++i) { a0[i] = 0.f; a1[i] = 0.f; }

        const float* xbase = xs + kbase * 64;
#pragma unroll 8
        for (int u = 0; u < 32; ++u) {
            const float* xrow = xbase + u * 64;
            float mm0 = m0[u], mm1 = m1[u];
#pragma unroll
            for (int q4 = 0; q4 < 4; ++q4) {
                float4 xq = *(const float4*)(xrow + ((p0 + q4 * 4) ^ psw));
                a0[q4*4+0] = fmaf(mm0, xq.x, a0[q4*4+0]);
                a0[q4*4+1] = fmaf(mm0, xq.y, a0[q4*4+1]);
                a0[q4*4+2] = fmaf(mm0, xq.z, a0[q4*4+2]);
                a0[q4*4+3] = fmaf(mm0, xq.w, a0[q4*4+3]);
                a1[q4*4+0] = fmaf(mm1, xq.x, a1[q4*4+0]);
                a1[q4*4+1] = fmaf(mm1, xq.y, a1[q4*4+1]);
                a1[q4*4+2] = fmaf(mm1, xq.z, a1[q4*4+2]);
                a1[q4*4+3] = fmaf(mm1, xq.w, a1[q4*4+3]);
            }
        }

        // combine k-quarters (kg = lane bits 4,5)
#pragma unroll
        for (int i = 0; i < 16; ++i) {
            a0[i] += __shfl_xor(a0[i], 16);
            a0[i] += __shfl_xor(a0[i], 32);
            a1[i] += __shfl_xor(a1[i], 16);
            a1[i] += __shfl_xor(a1[i], 32);
        }

        // epilogue: this lane finishes pixels p0 + kg*4 .. +3 (static indices)
        const int psw0 = (r0 >> 5) << 4;          // r0, r0+1 share k-group
        const float bias0 = cbs[r0], bias1 = cbs[r0 + 1];
#pragma unroll
        for (int i = 0; i < 4; ++i) {
            float s0 = kg == 0 ? a0[i] : kg == 1 ? a0[4+i] : kg == 2 ? a0[8+i] : a0[12+i];
            float s1 = kg == 0 ? a1[i] : kg == 1 ? a1[4+i] : kg == 2 ? a1[8+i] : a1[12+i];
            int p = p0 + kg * 4 + i;
            float x0 = xs[r0 * 64 + (p ^ psw0)];
            float x1 = xs[(r0 + 1) * 64 + (p ^ psw0)];
            float o0 = s0 + bias0;
            float o1 = s1 + bias1;
            float y0 = x0 + 0.5f * o0 * (1.f + erff(o0 * 0.70710678118654752f));
            float y1 = x1 + 0.5f * o1 * (1.f + erff(o1 * 0.70710678118654752f));
            __hip_bfloat162 pr;
            pr.x = __float2bfloat16(y0);
            pr.y = __float2bfloat16(y1);
            *(__hip_bfloat162*)(yt + p * 130 + r0) = pr;
        }
    }
    __syncthreads();

    // ---- LayerNorm stats: wave w owns pixels w*16..w*16+15, 4 lanes/pixel ----
    {
        int p = w * 16 + (l >> 2), sub = l & 3;
        const uint32_t* yr = (const uint32_t*)(yt + p * 130 + sub * 32);
        float s = 0.f, s2 = 0.f;
#pragma unroll
        for (int j = 0; j < 16; ++j) {
            uint32_t u = yr[j];
            float ylo = __uint_as_float(u << 16);
            float yhi = __uint_as_float(u & 0xffff0000u);
            s += ylo + yhi;
            s2 = fmaf(ylo, ylo, fmaf(yhi, yhi, s2));
        }
        s  += __shfl_xor(s, 1);  s  += __shfl_xor(s, 2);
        s2 += __shfl_xor(s2, 1); s2 += __shfl_xor(s2, 2);
        if (sub == 0) {
            float mean = s * (1.f / NN);
            float var  = s2 * (1.f / NN) - mean * mean;
            mu[p]  = mean;
            rsg[p] = rsqrtf(var + 1e-5f);
        }
    }
    __syncthreads();

    // ---- normalize + write out[b, c*64+p, v], float2 per thread-iter ----
    {
        float* op = out + ((size_t)b * GDIM + (size_t)c * LL) * NN;
#pragma unroll
        for (int kk = 0; kk < 16; ++kk) {
            int i = t + kk * 256;                 // 4096 bf16-pair slots
            int p = i >> 6, v = (i & 63) * 2;
            uint32_t u = *(const uint32_t*)(yt + p * 130 + v);
            float y0 = __uint_as_float(u << 16);
            float y1 = __uint_as_float(u & 0xffff0000u);
            float mm = mu[p], rr = rsg[p];
            float2 o2;
            o2.x = (y0 - mm) * rr * lnws[v]     + lnbs[v];
            o2.y = (y1 - mm) * rr * lnws[v + 1] + lnbs[v + 1];
            *(float2*)(op + p * NN + v) = o2;
        }
    }
}

// ---------------------------------------------------------------------------
extern "C" void kernel_launch(void* const* d_in, const int* in_sizes, int n_in,
                              void* d_out, int out_size, void* d_ws, size_t ws_size,
                              hipStream_t stream) {
    const float* x   = (const float*)d_in[0];
    const float* nv1 = (const float*)d_in[1];
    const float* nv2 = (const float*)d_in[2];
    const float* cw  = (const float*)d_in[3];
    const float* cb  = (const float*)d_in[4];
    const float* lnw = (const float*)d_in[5];
    const float* lnb = (const float*)d_in[6];
    float* out = (float*)d_out;

    // scratch: A, A2 live in d_out (fully overwritten by k_main afterwards);
    // Mreg lives in d_ws (64 KB) since k_main reads it while writing d_out.
    float* A    = out;
    float* A2   = out + NN * NN;
    float* Mreg = (float*)d_ws;

    k_adj<<<64, 128, 0, stream>>>(nv1, nv2, A);
    k_a2 <<<64, 256, 0, stream>>>(A, A2);
    k_m  <<<64, 256, 0, stream>>>(A, A2, cw, Mreg);
    k_main<<<dim3(CC, BB), 256, 0, stream>>>(x, Mreg, cb, lnw, lnb, out);
}

// Round 3
// 61.862 us; speedup vs baseline: 2.8506x; 2.2859x over previous
//
#include <hip/hip_runtime.h>
#include <hip/hip_bf16.h>
#include <math.h>

#define NN 128   // nodes (C_OUT)
#define ND 40    // node_dim
#define BB 32    // batch
#define CC 64    // channels
#define LL 64    // length
#define GDIM (CC*LL)  // 4096

typedef __attribute__((ext_vector_type(8))) short bf16x8;
typedef __attribute__((ext_vector_type(16))) float f32x16;

static __device__ __forceinline__ unsigned pk2(float a, float b) {
    __hip_bfloat162 h;
    h.x = __float2bfloat16(a);
    h.y = __float2bfloat16(b);
    return *(unsigned*)&h;
}

static __device__ __forceinline__ float gelu(float o) {
    return 0.5f * o * (1.f + erff(o * 0.70710678118654752f));
}

// ---------------------------------------------------------------------------
// K1: fused relu(nv1@nv2) + row softmax + self-loop + row-normalize -> A.
__global__ __launch_bounds__(128) void k_adj(const float* __restrict__ nv1,
                                             const float* __restrict__ nv2,
                                             float* __restrict__ A) {
    int t = threadIdx.x;
    int r = blockIdx.x * 2 + (t >> 6);
    int l = t & 63;
    float s0 = 0.f, s1 = 0.f;
#pragma unroll
    for (int k = 0; k < ND; ++k) {
        float a = nv1[r * ND + k];
        s0 = fmaf(a, nv2[k * NN + l], s0);
        s1 = fmaf(a, nv2[k * NN + 64 + l], s1);
    }
    s0 = fmaxf(s0, 0.f);
    s1 = fmaxf(s1, 0.f);
    float m = fmaxf(s0, s1);
#pragma unroll
    for (int d = 32; d; d >>= 1) m = fmaxf(m, __shfl_xor(m, d));
    float e0 = expf(s0 - m), e1 = expf(s1 - m);
    float ss = e0 + e1;
#pragma unroll
    for (int d = 32; d; d >>= 1) ss += __shfl_xor(ss, d);
    float p0 = e0 / ss, p1 = e1 / ss;
    float ps = p0 + p1;
#pragma unroll
    for (int d = 32; d; d >>= 1) ps += __shfl_xor(ps, d);
    float ra = 1.f / (ps + 1.f);
    A[r * NN + l]      = (p0 + (l == r ? 1.f : 0.f)) * ra;
    A[r * NN + 64 + l] = (p1 + ((l + 64) == r ? 1.f : 0.f)) * ra;
}

// ---------------------------------------------------------------------------
// K2: A2 = A @ A.
__global__ __launch_bounds__(256) void k_a2(const float* __restrict__ A,
                                            float* __restrict__ A2) {
    int idx = blockIdx.x * 256 + threadIdx.x;
    int w = idx >> 7, v = idx & (NN - 1);
    float s = 0.f;
    for (int u = 0; u < NN; ++u) s = fmaf(A[w * NN + u], A[u * NN + v], s);
    A2[idx] = s;
}

// ---------------------------------------------------------------------------
// K3: fold into Mfrag (bf16), MFMA-A-fragment-ready layout.
// M[o,v] = W0[o,v] + sum_w W1[o,w]*P[w,v] + W2[o,w]*H2[w,v]
//   P = 0.5 I + 0.5 A ;  H2 = 0.5 I + 0.25 A + 0.25 A^2
// k_main wave w lane l needs A-frag: M[w*32 + (l&31)][kk*16 + (l>>5)*8 + e].
// Layout (bf16 elems): Mfrag[kk*2048 + t*8 + e], t = (o>>5)*64 + ((v>>3)&1)*32 + (o&31).
__global__ __launch_bounds__(256) void k_m(const float* __restrict__ A,
                                           const float* __restrict__ A2,
                                           const float* __restrict__ W,
                                           short* __restrict__ Mfrag) {
    int idx = blockIdx.x * 256 + threadIdx.x;
    int o = idx >> 7, v = idx & (NN - 1);   // o = output row, v = k index
    float m = W[o * 384 + v];
    for (int w = 0; w < NN; ++w) {
        float d  = (w == v) ? 1.f : 0.f;
        float a  = A[w * NN + v];
        float a2 = A2[w * NN + v];
        float p  = 0.5f * d + 0.5f * a;
        float h2 = 0.5f * d + 0.25f * a + 0.25f * a2;
        m = fmaf(W[o * 384 + 128 + w], p, m);
        m = fmaf(W[o * 384 + 256 + w], h2, m);
    }
    int kk = v >> 4, hi = (v >> 3) & 1, e = v & 7;
    int tt = (o >> 5) * 64 + hi * 32 + (o & 31);
    __hip_bfloat16 hb = __float2bfloat16(m);
    Mfrag[kk * 2048 + tt * 8 + e] = *(short*)&hb;
}

// ---------------------------------------------------------------------------
// Main: one block per (b,c). 4 waves; wave w owns v rows [w*32, w*32+32),
// all 64 pixels as two 32x32 MFMA tiles. K=128 -> 8 x mfma_f32_32x32x16_bf16
// per tile. B from swizzled transposed bf16 LDS; A preloaded in VGPRs.
__global__ __launch_bounds__(256, 4) void k_main(const float* __restrict__ x,
                                                 const short* __restrict__ Mfrag,
                                                 const float* __restrict__ cb,
                                                 const float* __restrict__ lnw,
                                                 const float* __restrict__ lnb,
                                                 float* __restrict__ out) {
    __shared__ short xsT[LL * NN];            // [p][k] bf16, byte^=((p&15)<<4)
    __shared__ __hip_bfloat16 yt[LL * 130];   // [p][v], row stride 130
    __shared__ float cbs[NN], lnws[NN], lnbs[NN];
    __shared__ float mu[LL], rsg[LL];

    const int t = threadIdx.x;
    const int c = blockIdx.x, b = blockIdx.y;
    const int w = t >> 6, l = t & 63;

    // ---- A fragments: 8 x bf16x8 = 32 VGPRs, coalesced 16B/lane loads ----
    bf16x8 af[8];
#pragma unroll
    for (int kk = 0; kk < 8; ++kk)
        af[kk] = *(const bf16x8*)(Mfrag + kk * 2048 + t * 8);

    // ---- stage x -> xsT: 4x4 f32 micro-tile -> transpose -> b64 bf16 writes ----
    const float* xsrc = x + (size_t)b * NN * GDIM + (size_t)c * LL;
    char* xbb = (char*)xsT;
#pragma unroll
    for (int q = 0; q < 2; ++q) {
        int j = t + q * 256;
        int pq = j & 15, vq = j >> 4;        // vq 0..31, pq 0..15
        int pb = pq * 4;
        const float* rp = xsrc + (size_t)(vq * 4) * GDIM + pb;
        float4 r0 = *(const float4*)(rp);
        float4 r1 = *(const float4*)(rp + GDIM);
        float4 r2 = *(const float4*)(rp + 2 * GDIM);
        float4 r3 = *(const float4*)(rp + 3 * GDIM);
        float c0[4] = {r0.x, r0.y, r0.z, r0.w};
        float c1[4] = {r1.x, r1.y, r1.z, r1.w};
        float c2[4] = {r2.x, r2.y, r2.z, r2.w};
        float c3[4] = {r3.x, r3.y, r3.z, r3.w};
#pragma unroll
        for (int jj = 0; jj < 4; ++jj) {
            int p = pb + jj;
            uint2 wv;
            wv.x = pk2(c0[jj], c1[jj]);
            wv.y = pk2(c2[jj], c3[jj]);
            *(uint2*)(xbb + p * 256 + ((vq * 8) ^ ((p & 15) << 4))) = wv;
        }
    }
    if (t < NN) { cbs[t] = cb[t]; lnws[t] = lnw[t]; lnbs[t] = lnb[t]; }
    __syncthreads();

    // ---- MFMA K-loop ----
    const int hi = l >> 5;
    const int pc0 = l & 31, pc1 = 32 + (l & 31);
    const int sw = (l & 15) << 4;
    const char* xrb = (const char*)xsT;

    f32x16 acc0, acc1;
#pragma unroll
    for (int i = 0; i < 16; ++i) { acc0[i] = 0.f; acc1[i] = 0.f; }

#pragma unroll
    for (int kk = 0; kk < 8; ++kk) {
        int kb = kk * 32 + hi * 16;
        bf16x8 b0 = *(const bf16x8*)(xrb + pc0 * 256 + (kb ^ sw));
        bf16x8 b1 = *(const bf16x8*)(xrb + pc1 * 256 + (kb ^ sw));
        acc0 = __builtin_amdgcn_mfma_f32_32x32x16_bf16(af[kk], b0, acc0, 0, 0, 0);
        acc1 = __builtin_amdgcn_mfma_f32_32x32x16_bf16(af[kk], b1, acc1, 0, 0, 0);
    }

    // ---- epilogue: D layout col=lane&31, row=(r&3)+8*(r>>2)+4*(lane>>5) ----
    // residual x re-read from global in f32 (L3-resident), bias+GELU, pack
    // bf16 pairs into yt[p][v] (stride 130 -> conflict-free).
    const int vh = hi * 4;
    char* ytb = (char*)yt;
#pragma unroll
    for (int g = 0; g < 4; ++g) {
        const int vb = w * 32 + g * 8 + vh;
        const float cb0 = cbs[vb], cb1 = cbs[vb + 1], cb2 = cbs[vb + 2], cb3 = cbs[vb + 3];
        {
            const float* xp = xsrc + (size_t)vb * GDIM + pc0;
            float y0 = xp[0]        + gelu(acc0[4 * g + 0] + cb0);
            float y1 = xp[GDIM]     + gelu(acc0[4 * g + 1] + cb1);
            float y2 = xp[2 * GDIM] + gelu(acc0[4 * g + 2] + cb2);
            float y3 = xp[3 * GDIM] + gelu(acc0[4 * g + 3] + cb3);
            *(unsigned*)(ytb + pc0 * 260 + vb * 2)     = pk2(y0, y1);
            *(unsigned*)(ytb + pc0 * 260 + vb * 2 + 4) = pk2(y2, y3);
        }
        {
            const float* xp = xsrc + (size_t)vb * GDIM + pc1;
            float y0 = xp[0]        + gelu(acc1[4 * g + 0] + cb0);
            float y1 = xp[GDIM]     + gelu(acc1[4 * g + 1] + cb1);
            float y2 = xp[2 * GDIM] + gelu(acc1[4 * g + 2] + cb2);
            float y3 = xp[3 * GDIM] + gelu(acc1[4 * g + 3] + cb3);
            *(unsigned*)(ytb + pc1 * 260 + vb * 2)     = pk2(y0, y1);
            *(unsigned*)(ytb + pc1 * 260 + vb * 2 + 4) = pk2(y2, y3);
        }
    }
    __syncthreads();

    // ---- LayerNorm stats: wave w owns pixels w*16..+15, 4 lanes/pixel ----
    {
        int p = w * 16 + (l >> 2), sub = l & 3;
        const unsigned* yr = (const unsigned*)((const char*)yt + p * 260 + sub * 64);
        float s = 0.f, s2 = 0.f;
#pragma unroll
        for (int j = 0; j < 16; ++j) {
            unsigned u = yr[j];
            float ylo = __uint_as_float(u << 16);
            float yhi = __uint_as_float(u & 0xffff0000u);
            s += ylo + yhi;
            s2 = fmaf(ylo, ylo, fmaf(yhi, yhi, s2));
        }
        s  += __shfl_xor(s, 1);  s  += __shfl_xor(s, 2);
        s2 += __shfl_xor(s2, 1); s2 += __shfl_xor(s2, 2);
        if (sub == 0) {
            float mean = s * (1.f / NN);
            float var  = s2 * (1.f / NN) - mean * mean;
            mu[p]  = mean;
            rsg[p] = rsqrtf(var + 1e-5f);
        }
    }
    __syncthreads();

    // ---- normalize + write out[b, c*64+p, v] ----
    {
        float* op = out + ((size_t)b * GDIM + (size_t)c * LL) * NN;
#pragma unroll
        for (int kk = 0; kk < 16; ++kk) {
            int i = t + kk * 256;
            int p = i >> 6, v = (i & 63) * 2;
            unsigned u = *(const unsigned*)((const char*)yt + p * 260 + v * 2);
            float y0 = __uint_as_float(u << 16);
            float y1 = __uint_as_float(u & 0xffff0000u);
            float mm = mu[p], rr = rsg[p];
            float2 o2;
            o2.x = (y0 - mm) * rr * lnws[v]     + lnbs[v];
            o2.y = (y1 - mm) * rr * lnws[v + 1] + lnbs[v + 1];
            *(float2*)(op + p * NN + v) = o2;
        }
    }
}

// ---------------------------------------------------------------------------
extern "C" void kernel_launch(void* const* d_in, const int* in_sizes, int n_in,
                              void* d_out, int out_size, void* d_ws, size_t ws_size,
                              hipStream_t stream) {
    const float* x   = (const float*)d_in[0];
    const float* nv1 = (const float*)d_in[1];
    const float* nv2 = (const float*)d_in[2];
    const float* cw  = (const float*)d_in[3];
    const float* cb  = (const float*)d_in[4];
    const float* lnw = (const float*)d_in[5];
    const float* lnb = (const float*)d_in[6];
    float* out = (float*)d_out;

    // scratch: A, A2 in d_out (fully overwritten by k_main); Mfrag (32 KB) in d_ws.
    float* A    = out;
    float* A2   = out + NN * NN;
    short* Mfrag = (short*)d_ws;

    k_adj<<<64, 128, 0, stream>>>(nv1, nv2, A);
    k_a2 <<<64, 256, 0, stream>>>(A, A2);
    k_m  <<<64, 256, 0, stream>>>(A, A2, cw, Mfrag);
    k_main<<<dim3(CC, BB), 256, 0, stream>>>(x, Mfrag, cb, lnw, lnb, out);
}